// Round 2
// baseline (643.669 us; speedup 1.0000x reference)
//
#include <hip/hip_runtime.h>

#define TSTEPS 128
#define BATCH  4096
#define WPB    16      // waves per block (block = 1024 threads)

// LDS float-offset layout (all weights stored TRANSPOSED: WT[j][i] = W[i][j])
#define OFF_WTIN 0              // 64x64   -> [0,4096)
#define OFF_WT1  4096           // 64x32   -> [4096,6144)
#define OFF_WTH  6144           // 6 x 32x32 -> [6144,12288)
#define OFF_WTA  12288          // 32x400  -> [12288,25088)
#define OFF_WC   25088          // 32      -> [25088,25120)
#define OFF_TAB  25120          // 101-entry sequential 0.01f sum table
#define OFF_XBUF 25224          // 16 waves x 64 floats
#define LDS_FLOATS (OFF_XBUF + WPB * 64)
#define LDS_BYTES  (LDS_FLOATS * 4)

// strict-f32 LIF: reset uses PREVIOUS mem; op order ((beta*m)+cur)-(reset*thr),
// each op rounded separately (numpy semantics; intrinsics block fp-contract)
#define LIF(M, CUR, BETA, THR) {                                           \
    float r_ = ((M) > (THR)) ? (THR) : 0.0f;                               \
    (M) = __fsub_rn(__fadd_rn(__fmul_rn((BETA), (M)), (CUR)), r_); }

// spike dot: ascending set-bit order, single f32 accumulator chain
// (== sgemm's ascending-k fma chain; zero-spike terms are exact no-ops)
#define HDOT32(MASK, COLP, OUTV) {                                         \
    float acc_ = 0.0f; unsigned mm_ = (MASK);                              \
    while (mm_) {                                                          \
      int j_ = __builtin_ctz(mm_); mm_ &= mm_ - 1;                         \
      acc_ = __fadd_rn(acc_, (COLP)[j_ * 32]);                             \
    }                                                                      \
    OUTV = acc_; }

extern "C" __global__ __launch_bounds__(1024, 1)
void snn_actor_critic(const float* __restrict__ inputs,
                      const float* __restrict__ Win, const float* __restrict__ bin_,
                      const float* __restrict__ W1,  const float* __restrict__ b1,
                      const float* __restrict__ W2,  const float* __restrict__ b2,
                      const float* __restrict__ W3,  const float* __restrict__ b3,
                      const float* __restrict__ W4,  const float* __restrict__ b4,
                      const float* __restrict__ W5,  const float* __restrict__ b5,
                      const float* __restrict__ W6,  const float* __restrict__ b6,
                      const float* __restrict__ W7,  const float* __restrict__ b7,
                      const float* __restrict__ Wa,  const float* __restrict__ ba,
                      const float* __restrict__ Wc,  const float* __restrict__ bc,
                      const float* __restrict__ betac, const float* __restrict__ am,
                      float* __restrict__ out)
{
  extern __shared__ float lds[];
  const int tid  = threadIdx.x;
  const int lane = tid & 63;
  const int l32  = lane & 31;

  // ---- stage transposed weights into LDS ----
  #pragma unroll
  for (int it = 0; it < 4; ++it) {          // W_in 64x64
    int idx = tid + it * 1024; int i = idx >> 6, j = idx & 63;
    lds[OFF_WTIN + j * 64 + i] = Win[idx];
  }
  #pragma unroll
  for (int it = 0; it < 2; ++it) {          // W1 32x64
    int idx = tid + it * 1024; int i = idx >> 6, j = idx & 63;
    lds[OFF_WT1 + j * 32 + i] = W1[idx];
  }
  {                                         // W2..W7 32x32 each
    int i = tid >> 5, j = tid & 31; int d = j * 32 + i;
    lds[OFF_WTH + 0 * 1024 + d] = W2[tid];
    lds[OFF_WTH + 1 * 1024 + d] = W3[tid];
    lds[OFF_WTH + 2 * 1024 + d] = W4[tid];
    lds[OFF_WTH + 3 * 1024 + d] = W5[tid];
    lds[OFF_WTH + 4 * 1024 + d] = W6[tid];
    lds[OFF_WTH + 5 * 1024 + d] = W7[tid];
  }
  for (int idx = tid; idx < 12800; idx += 1024) {   // W_actor 400x32
    int k = idx >> 5, j = idx & 31;
    lds[OFF_WTA + j * 400 + k] = Wa[idx];
  }
  if (tid < 32) lds[OFF_WC + tid] = Wc[tid];
  if (tid == 0) {                           // sequential-sum table: n adds of 0.01f
    float a = 0.0f; lds[OFF_TAB] = 0.0f; float step = am[0];
    for (int n = 1; n <= 100; ++n) { a = __fadd_rn(a, step); lds[OFF_TAB + n] = a; }
  }

  // ---- biases / consts into registers (f32) ----
  float bin_f = bin_[lane];
  float bh0 = b1[l32], bh1 = b2[l32], bh2 = b3[l32], bh3 = b4[l32],
        bh4 = b5[l32], bh5 = b6[l32], bh6 = b7[l32];
  float ba0 = ba[lane],       ba1 = ba[lane + 64],  ba2 = ba[lane + 128],
        ba3 = ba[lane + 192], ba4 = ba[lane + 256], ba5 = ba[lane + 320],
        ba6 = (lane < 16) ? ba[lane + 384] : 0.0f;
  float bc_f    = bc[0];
  float beta_cf = betac[0];

  __syncthreads();

  // ---- per-wave batch element ----
  const int  wave = tid >> 6;
  const long b    = (long)blockIdx.x * WPB + wave;
  float* xw = lds + OFF_XBUF + wave * 64;
  const float* wcol = lds + OFF_WTIN + lane;
  const float* col1 = lds + OFF_WT1  + l32;
  const float* colh = lds + OFF_WTH  + l32;
  const float* wab  = lds + OFF_WTA  + lane;
  const float* wcp  = lds + OFF_WC;
  const float* tab  = lds + OFF_TAB;
  const float* inp  = inputs + b * 64 + lane;
  float* vout = out + b;                                   // vals[t*B + b]
  float* aout = out + (long)TSTEPS * BATCH + b * 4 + lane; // actions[(t*B+b)*4 + a]

  float m_in = 0.0f;
  float mh0 = 0.0f, mh1 = 0.0f, mh2 = 0.0f, mh3 = 0.0f, mh4 = 0.0f, mh5 = 0.0f, mh6 = 0.0f;
  float ma0 = 0.0f, ma1 = 0.0f, ma2 = 0.0f, ma3 = 0.0f, ma4 = 0.0f, ma5 = 0.0f, ma6 = 0.0f;
  float mc  = 0.0f;

  for (int t = 0; t < TSTEPS; ++t) {
    xw[lane] = inp[(long)t * (BATCH * 64)];

    // ---- input layer: dense 64-dot, single ascending fma chain ----
    float acc = 0.0f;
    #pragma unroll
    for (int j = 0; j < 64; ++j)
      acc = __builtin_fmaf(xw[j], wcol[j * 64], acc);
    float cur = __fadd_rn(acc, bin_f);
    LIF(m_in, cur, 0.65f, 0.25f);
    unsigned long long s64 = __ballot(__fsub_rn(m_in, 0.25f) > 0.0f);

    // ---- L1: 64-bit spike mask -> 32 outputs (lanes 32-63 mirror 0-31) ----
    float d1 = 0.0f;
    { unsigned long long mm_ = s64;
      while (mm_) {
        int j_ = (int)__builtin_ctzll(mm_); mm_ &= mm_ - 1;
        d1 = __fadd_rn(d1, col1[j_ * 32]);
      } }
    float cur1 = __fadd_rn(d1, bh0);
    LIF(mh0, cur1, 0.65f, 0.25f);
    unsigned k1 = (unsigned)__ballot(__fsub_rn(mh0, 0.25f) > 0.0f);

    // ---- L2..L7 ----
    float d2; HDOT32(k1, colh + 0 * 1024, d2);
    float cur2 = __fadd_rn(d2, bh1);
    LIF(mh1, cur2, 0.85f, 1.0f);
    unsigned k2 = (unsigned)__ballot(__fsub_rn(mh1, 1.0f) > 0.0f);

    float d3; HDOT32(k2, colh + 1 * 1024, d3);
    float cur3 = __fadd_rn(d3, bh2);
    LIF(mh2, cur3, 0.85f, 1.0f);
    unsigned k3 = (unsigned)__ballot(__fsub_rn(mh2, 1.0f) > 0.0f);

    float d4; HDOT32(k3, colh + 2 * 1024, d4);
    float cur4 = __fadd_rn(d4, bh3);
    LIF(mh3, cur4, 0.95f, 1.0f);
    unsigned k4 = (unsigned)__ballot(__fsub_rn(mh3, 1.0f) > 0.0f);

    float d5; HDOT32(k4, colh + 3 * 1024, d5);
    float cur5 = __fadd_rn(d5, bh4);
    LIF(mh4, cur5, 0.95f, 1.0f);
    unsigned k5 = (unsigned)__ballot(__fsub_rn(mh4, 1.0f) > 0.0f);

    float d6; HDOT32(k5, colh + 4 * 1024, d6);
    float cur6 = __fadd_rn(d6, bh5);
    LIF(mh5, cur6, 0.95f, 1.0f);
    unsigned k6 = (unsigned)__ballot(__fsub_rn(mh5, 1.0f) > 0.0f);

    float d7; HDOT32(k6, colh + 5 * 1024, d7);
    float cur7 = __fadd_rn(d7, bh6);
    LIF(mh6, cur7, 0.95f, 1.0f);
    unsigned k7 = (unsigned)__ballot(__fsub_rn(mh6, 1.0f) > 0.0f);

    // ---- actor: 400 outputs, lane handles k = lane + 64r ----
    float ca0 = 0.0f, ca1 = 0.0f, ca2 = 0.0f, ca3 = 0.0f, ca4 = 0.0f, ca5 = 0.0f, ca6 = 0.0f;
    { unsigned mm_ = k7;
      while (mm_) {
        int j_ = __builtin_ctz(mm_); mm_ &= mm_ - 1;
        const float* rp = wab + j_ * 400;
        ca0 = __fadd_rn(ca0, rp[0]);   ca1 = __fadd_rn(ca1, rp[64]);
        ca2 = __fadd_rn(ca2, rp[128]); ca3 = __fadd_rn(ca3, rp[192]);
        ca4 = __fadd_rn(ca4, rp[256]); ca5 = __fadd_rn(ca5, rp[320]);
        ca6 = __fadd_rn(ca6, rp[384]);   // garbage for lane>=16; masked below
      } }
    float cua0 = __fadd_rn(ca0, ba0), cua1 = __fadd_rn(ca1, ba1),
          cua2 = __fadd_rn(ca2, ba2), cua3 = __fadd_rn(ca3, ba3),
          cua4 = __fadd_rn(ca4, ba4), cua5 = __fadd_rn(ca5, ba5),
          cua6 = __fadd_rn(ca6, ba6);
    unsigned long long sa0, sa1, sa2, sa3, sa4, sa5, sa6;
    LIF(ma0, cua0, 0.95f, 1.0f); sa0 = __ballot(__fsub_rn(ma0, 1.0f) > 0.0f);
    LIF(ma1, cua1, 0.95f, 1.0f); sa1 = __ballot(__fsub_rn(ma1, 1.0f) > 0.0f);
    LIF(ma2, cua2, 0.95f, 1.0f); sa2 = __ballot(__fsub_rn(ma2, 1.0f) > 0.0f);
    LIF(ma3, cua3, 0.95f, 1.0f); sa3 = __ballot(__fsub_rn(ma3, 1.0f) > 0.0f);
    LIF(ma4, cua4, 0.95f, 1.0f); sa4 = __ballot(__fsub_rn(ma4, 1.0f) > 0.0f);
    LIF(ma5, cua5, 0.95f, 1.0f); sa5 = __ballot(__fsub_rn(ma5, 1.0f) > 0.0f);
    LIF(ma6, cua6, 0.95f, 1.0f); sa6 = __ballot(__fsub_rn(ma6, 1.0f) > 0.0f);

    // group counts (actor neuron k = 64r + bit; group = k/100)
    int c0 = __popcll(sa0) + __popcll(sa1 & 0xFFFFFFFFFULL);
    int c1 = __popcll(sa1 >> 36) + __popcll(sa2) + __popcll(sa3 & 0xFFULL);
    int c2 = __popcll(sa3 >> 8) + __popcll(sa4 & 0xFFFFFFFFFFFULL);
    int c3 = __popcll(sa4 >> 44) + __popcll(sa5) + __popcll(sa6 & 0xFFFFULL);

    // ---- critic (all lanes redundant, identical) ----
    float cc = 0.0f;
    { unsigned mm_ = k7;
      while (mm_) { int j_ = __builtin_ctz(mm_); mm_ &= mm_ - 1;
                    cc = __fadd_rn(cc, wcp[j_]); } }
    float curc = __fadd_rn(cc, bc_f);
    LIF(mc, curc, beta_cf, 100.0f);

    // ---- outputs ----
    if (lane == 0) vout[(long)t * BATCH] = mc;
    if (lane < 4) {
      int cnt = (lane == 0) ? c0 : (lane == 1) ? c1 : (lane == 2) ? c2 : c3;
      aout[(long)t * BATCH * 4] = tab[cnt];  // n sequential adds of 0.01f
    }
  }
}

extern "C" void kernel_launch(void* const* d_in, const int* in_sizes, int n_in,
                              void* d_out, int out_size, void* d_ws, size_t ws_size,
                              hipStream_t stream) {
  (void)in_sizes; (void)n_in; (void)out_size; (void)d_ws; (void)ws_size;
  hipFuncSetAttribute((const void*)snn_actor_critic,
                      hipFuncAttributeMaxDynamicSharedMemorySize, LDS_BYTES);
  const float* I    = (const float*)d_in[0];
  const float* Win  = (const float*)d_in[1];  const float* bin_ = (const float*)d_in[2];
  const float* W1   = (const float*)d_in[3];  const float* b1   = (const float*)d_in[4];
  const float* W2   = (const float*)d_in[5];  const float* b2   = (const float*)d_in[6];
  const float* W3   = (const float*)d_in[7];  const float* b3   = (const float*)d_in[8];
  const float* W4   = (const float*)d_in[9];  const float* b4   = (const float*)d_in[10];
  const float* W5   = (const float*)d_in[11]; const float* b5   = (const float*)d_in[12];
  const float* W6   = (const float*)d_in[13]; const float* b6   = (const float*)d_in[14];
  const float* W7   = (const float*)d_in[15]; const float* b7   = (const float*)d_in[16];
  const float* Wa   = (const float*)d_in[17]; const float* ba   = (const float*)d_in[18];
  const float* Wc   = (const float*)d_in[19]; const float* bc   = (const float*)d_in[20];
  const float* betc = (const float*)d_in[21]; const float* am   = (const float*)d_in[22];
  float* out = (float*)d_out;

  snn_actor_critic<<<dim3(BATCH / WPB), dim3(1024), LDS_BYTES, stream>>>(
      I, Win, bin_, W1, b1, W2, b2, W3, b3, W4, b4, W5, b5, W6, b6, W7, b7,
      Wa, ba, Wc, bc, betc, am, out);
}